// Round 15
// baseline (168.145 us; speedup 1.0000x reference)
//
#include <hip/hip_runtime.h>

#define N_NODES 100000
#define N_EDGES 3200000
#define IN_DIM  128
#define HID     16
#define OUTC    2

// bucket geometry
#define NB     128                    // dst-range buckets
#define SPAN   782                    // nodes per bucket (128*782 >= N)
#define CAP    26500                  // per-bucket capacity
#define NBLK   800                    // bucketing blocks
#define BLK_E  (N_EDGES / NBLK)       // 4000
#define S0     16                     // splits per bucket (hist + csrfill)

// node-scan geometry
#define SCAN_ELEMS 2048
#define SCAN_NB    49                 // ceil(100000/2048)

__device__ __forceinline__ unsigned short f2b(float f) {
    unsigned u = __float_as_uint(f);
    unsigned r = u + 0x7FFFu + ((u >> 16) & 1u);   // round-to-nearest-even
    return (unsigned short)(r >> 16);
}
__device__ __forceinline__ float b2f(unsigned short b) {
    return __uint_as_float(((unsigned)b) << 16);
}

// ---------------- K1a: per-(block,bucket) counts ----------------
__global__ __launch_bounds__(256) void k_count_bb(const int* __restrict__ dst,
                                                  int* __restrict__ bc) {
    __shared__ int h[NB];
    if (threadIdx.x < NB) h[threadIdx.x] = 0;
    __syncthreads();
    const int4* d4 = (const int4*)(dst + blockIdx.x * BLK_E);
    for (int i = threadIdx.x; i < BLK_E / 4; i += 256) {
        int4 v = d4[i];
        atomicAdd(&h[(unsigned)v.x / SPAN], 1);
        atomicAdd(&h[(unsigned)v.y / SPAN], 1);
        atomicAdd(&h[(unsigned)v.z / SPAN], 1);
        atomicAdd(&h[(unsigned)v.w / SPAN], 1);
    }
    __syncthreads();
    if (threadIdx.x < NB) bc[blockIdx.x * NB + threadIdx.x] = h[threadIdx.x];
}

// ---------------- K1b: parallel exclusive scan per bucket over NBLK blocks ----------------
__global__ __launch_bounds__(256) void k_scan_bb(int* __restrict__ bc,
                                                 int* __restrict__ bcount) {
    __shared__ int s[256];
    int b = blockIdx.x;              // bucket
    int base = threadIdx.x * 4;      // 4 block-counts per thread (256*4 >= 800)
    int vals[4];
    int tsum = 0;
#pragma unroll
    for (int i = 0; i < 4; ++i) {
        int t = base + i;
        vals[i] = (t < NBLK) ? bc[t * NB + b] : 0;
        tsum += vals[i];
    }
    s[threadIdx.x] = tsum;
    __syncthreads();
    for (int ofs = 1; ofs < 256; ofs <<= 1) {
        int u = (threadIdx.x >= ofs) ? s[threadIdx.x - ofs] : 0;
        __syncthreads();
        s[threadIdx.x] += u;
        __syncthreads();
    }
    int run = s[threadIdx.x] - tsum;   // exclusive prefix
#pragma unroll
    for (int i = 0; i < 4; ++i) {
        int t = base + i;
        if (t < NBLK) { bc[t * NB + b] = run; run += vals[i]; }
    }
    if (threadIdx.x == 255) bcount[b] = s[255];
}

// ---------------- K1c: fill buckets with (src,dst) int2 pairs ----------------
__global__ __launch_bounds__(256) void k_fillbkt(const int* __restrict__ src,
                                                 const int* __restrict__ dst,
                                                 const int* __restrict__ bc,
                                                 int2* __restrict__ bpair) {
    __shared__ int h[NB];
    __shared__ int gb[NB];
    if (threadIdx.x < NB) {
        h[threadIdx.x] = 0;
        gb[threadIdx.x] = threadIdx.x * CAP + bc[blockIdx.x * NB + threadIdx.x];
    }
    __syncthreads();
    const int4* d4 = (const int4*)(dst + blockIdx.x * BLK_E);
    const int4* s4 = (const int4*)(src + blockIdx.x * BLK_E);
    for (int i = threadIdx.x; i < BLK_E / 4; i += 256) {
        int4 dv = d4[i];
        int4 sv = s4[i];
        int b0 = (unsigned)dv.x / SPAN; int p0 = gb[b0] + atomicAdd(&h[b0], 1); bpair[p0] = make_int2(sv.x, dv.x);
        int b1 = (unsigned)dv.y / SPAN; int p1 = gb[b1] + atomicAdd(&h[b1], 1); bpair[p1] = make_int2(sv.y, dv.y);
        int b2 = (unsigned)dv.z / SPAN; int p2 = gb[b2] + atomicAdd(&h[b2], 1); bpair[p2] = make_int2(sv.z, dv.z);
        int b3 = (unsigned)dv.w / SPAN; int p3 = gb[b3] + atomicAdd(&h[b3], 1); bpair[p3] = make_int2(sv.w, dv.w);
    }
}

// ---------------- K2: per-node degree histogram, S0 splits ----------------
__global__ __launch_bounds__(256) void k_cnt_nodes(const int2* __restrict__ bpair,
                                                   const int* __restrict__ bcount,
                                                   int* __restrict__ pcnt) {
    __shared__ int h[SPAN];
    int b = blockIdx.x / S0, s = blockIdx.x % S0;
    for (int i = threadIdx.x; i < SPAN; i += 256) h[i] = 0;
    __syncthreads();
    int tot = bcount[b];
    int lo = tot * s / S0, hi = tot * (s + 1) / S0;
    const int2* bp = bpair + (size_t)b * CAP;
    int base = b * SPAN;
    for (int i = lo + threadIdx.x; i < hi; i += 256)
        atomicAdd(&h[bp[i].y - base], 1);
    __syncthreads();
    for (int j = threadIdx.x; j < SPAN; j += 256)
        pcnt[(size_t)blockIdx.x * SPAN + j] = h[j];
}

// ---------------- K2b: cnt + dinv ----------------
__global__ __launch_bounds__(256) void k_cntsum(const int* __restrict__ pcnt,
                                                int* __restrict__ cnt,
                                                float* __restrict__ dinv) {
    int n = blockIdx.x * 256 + threadIdx.x;
    if (n >= N_NODES) return;
    unsigned b = (unsigned)n / SPAN, l = n - b * SPAN;
    int c = 0;
#pragma unroll
    for (int s = 0; s < S0; ++s)
        c += pcnt[(size_t)(b * S0 + s) * SPAN + l];
    cnt[n] = c;
    dinv[n] = rsqrtf(1.0f + (float)c);   // + self-loop
}

// ---------------- node scan ----------------
__global__ __launch_bounds__(256) void k_blocksum(const int* __restrict__ cnt,
                                                  int* __restrict__ bsum) {
    __shared__ int s[256];
    int base = blockIdx.x * SCAN_ELEMS + threadIdx.x * 8;
    int t = 0;
#pragma unroll
    for (int i = 0; i < 8; ++i) {
        int idx = base + i;
        t += (idx < N_NODES) ? cnt[idx] : 0;
    }
    s[threadIdx.x] = t;
    __syncthreads();
    for (int ofs = 128; ofs > 0; ofs >>= 1) {
        if (threadIdx.x < ofs) s[threadIdx.x] += s[threadIdx.x + ofs];
        __syncthreads();
    }
    if (threadIdx.x == 0) bsum[blockIdx.x] = s[0];
}

__global__ __launch_bounds__(64) void k_scanb(const int* __restrict__ bsum,
                                              int* __restrict__ boff) {
    if (threadIdx.x == 0) {
        int run = 0;
        for (int b = 0; b < SCAN_NB; ++b) { boff[b] = run; run += bsum[b]; }
    }
}

// offsets + fused pcnt->csr-base conversion
__global__ __launch_bounds__(256) void k_offsets(const int* __restrict__ cnt,
                                                 const int* __restrict__ boff,
                                                 int* __restrict__ off,
                                                 int* __restrict__ pcnt) {
    __shared__ int s[256];
    int base = blockIdx.x * SCAN_ELEMS + threadIdx.x * 8;
    int c[8];
    int tsum = 0;
#pragma unroll
    for (int i = 0; i < 8; ++i) {
        int idx = base + i;
        c[i] = (idx < N_NODES) ? cnt[idx] : 0;
        tsum += c[i];
    }
    s[threadIdx.x] = tsum;
    __syncthreads();
    for (int ofs = 1; ofs < 256; ofs <<= 1) {
        int v = (threadIdx.x >= ofs) ? s[threadIdx.x - ofs] : 0;
        __syncthreads();
        s[threadIdx.x] += v;
        __syncthreads();
    }
    int tbase = boff[blockIdx.x] + s[threadIdx.x] - tsum;
    int run = 0;
#pragma unroll
    for (int i = 0; i < 8; ++i) {
        int idx = base + i;
        if (idx < N_NODES) {
            int o = tbase + run;
            off[idx] = o;
            unsigned bb = (unsigned)idx / SPAN, l = idx - bb * SPAN;
            int r2 = o;
#pragma unroll
            for (int sp = 0; sp < S0; ++sp) {
                size_t id2 = (size_t)(bb * S0 + sp) * SPAN + l;
                int v = pcnt[id2];
                pcnt[id2] = r2;
                r2 += v;
            }
        }
        run += c[i];
    }
}

// ---------------- K2d: fill CSR from buckets (LDS-ranked, split-major XCD-local) ----------------
__global__ __launch_bounds__(256) void k_csrfill(const int2* __restrict__ bpair,
                                                 const int* __restrict__ bcount,
                                                 const int* __restrict__ pcnt, // bases
                                                 int* __restrict__ csr) {
    __shared__ int rank[SPAN];
    int b = blockIdx.x % NB, s = blockIdx.x / NB;
    for (int i = threadIdx.x; i < SPAN; i += 256)
        rank[i] = pcnt[(size_t)(b * S0 + s) * SPAN + i];
    __syncthreads();
    int tot = bcount[b];
    int lo = tot * s / S0, hi = tot * (s + 1) / S0;
    int base = b * SPAN;
    const int2* bp = bpair + (size_t)b * CAP;
    for (int i = lo + threadIdx.x; i < hi; i += 256) {
        int2 e = bp[i];
        int r = atomicAdd(&rank[e.y - base], 1);
        csr[r] = e.x;
    }
}

// ---------------- K3: p1b(bf16) = dinv * (x @ W1) — one thread per node ----------------
__global__ __launch_bounds__(256) void k_gemm1(const float* __restrict__ x,
                                               const float* __restrict__ W1,
                                               const float* __restrict__ dinv,
                                               unsigned short* __restrict__ p1b) {
    int n = blockIdx.x * 256 + threadIdx.x;
    if (n >= N_NODES) return;

    float acc[HID];
#pragma unroll
    for (int k = 0; k < HID; ++k) acc[k] = 0.f;

    const float4* xr = (const float4*)(x + (size_t)n * IN_DIM);
#pragma unroll 4
    for (int q = 0; q < IN_DIM / 4; ++q) {
        float4 xv = xr[q];
        const float* wrow = W1 + q * 4 * HID;   // uniform -> scalar loads
#pragma unroll
        for (int k = 0; k < HID; ++k) acc[k] = fmaf(xv.x, wrow[0 * HID + k], acc[k]);
#pragma unroll
        for (int k = 0; k < HID; ++k) acc[k] = fmaf(xv.y, wrow[1 * HID + k], acc[k]);
#pragma unroll
        for (int k = 0; k < HID; ++k) acc[k] = fmaf(xv.z, wrow[2 * HID + k], acc[k]);
#pragma unroll
        for (int k = 0; k < HID; ++k) acc[k] = fmaf(xv.w, wrow[3 * HID + k], acc[k]);
    }

    float di = dinv[n];
    union { unsigned short us[HID]; uint4 v4[2]; } pk;
#pragma unroll
    for (int k = 0; k < HID; ++k) pk.us[k] = f2b(acc[k] * di);
    uint4* op = (uint4*)(p1b + (size_t)n * HID);
    op[0] = pk.v4[0];
    op[1] = pk.v4[1];
}

// ---------------- K4: node-parallel gather 1 (+relu/b1 and W2 fused) ----------------
__global__ __launch_bounds__(256) void k_gather1(const int* __restrict__ csr,
                                                 const int* __restrict__ off,
                                                 const int* __restrict__ cnt,
                                                 const unsigned short* __restrict__ p1b,
                                                 const float* __restrict__ dinv,
                                                 const float* __restrict__ b1,
                                                 const float* __restrict__ W2,
                                                 float* __restrict__ p2b) {
    int gid = blockIdx.x * 256 + threadIdx.x;
    int n = gid >> 4;
    int k = gid & 15;
    if (n >= N_NODES) return;

    int base = off[n];
    int deg = cnt[n];
    float acc = 0.f;
    int j = 0;
    for (; j + 3 < deg; j += 4) {
        int s0 = csr[base + j + 0];
        int s1 = csr[base + j + 1];
        int s2 = csr[base + j + 2];
        int s3 = csr[base + j + 3];
        float v0 = b2f(p1b[s0 * HID + k]);
        float v1 = b2f(p1b[s1 * HID + k]);
        float v2 = b2f(p1b[s2 * HID + k]);
        float v3 = b2f(p1b[s3 * HID + k]);
        acc += (v0 + v1) + (v2 + v3);
    }
    for (; j < deg; ++j) acc += b2f(p1b[csr[base + j] * HID + k]);
    acc += b2f(p1b[n * HID + k]);                // self-loop

    float di = dinv[n];
    float hval = fmaxf(fmaf(di, acc, b1[k]), 0.f);
    float hv = di * hval;
    float t0 = hv * W2[k * OUTC + 0];
    float t1 = hv * W2[k * OUTC + 1];
#pragma unroll
    for (int m = 1; m < HID; m <<= 1) {
        t0 += __shfl_xor(t0, m);
        t1 += __shfl_xor(t1, m);
    }
    if (k == 0) *(float2*)(p2b + n * OUTC) = make_float2(t0, t1);
}

// ---------------- K5: node-parallel gather 2 (+b2/log_softmax fused) ----------------
__global__ __launch_bounds__(256) void k_gather2(const int* __restrict__ csr,
                                                 const int* __restrict__ off,
                                                 const int* __restrict__ cnt,
                                                 const float* __restrict__ p2b,
                                                 const float* __restrict__ dinv,
                                                 const float* __restrict__ b2,
                                                 float* __restrict__ out) {
    int gid = blockIdx.x * 256 + threadIdx.x;
    int n = gid >> 4;
    int k = gid & 15;
    if (n >= N_NODES) return;

    int base = off[n];
    int deg = cnt[n];
    float a0 = 0.f, a1 = 0.f;
    for (int j = k; j < deg; j += 16) {
        int s = csr[base + j];
        float2 v = *(const float2*)(p2b + s * OUTC);
        a0 += v.x;
        a1 += v.y;
    }
    if (k == 0) {                                // self-loop
        float2 v = *(const float2*)(p2b + n * OUTC);
        a0 += v.x;
        a1 += v.y;
    }
#pragma unroll
    for (int m = 1; m < HID; m <<= 1) {
        a0 += __shfl_xor(a0, m);
        a1 += __shfl_xor(a1, m);
    }
    if (k == 0) {
        float di = dinv[n];
        float v0 = fmaf(di, a0, b2[0]);
        float v1 = fmaf(di, a1, b2[1]);
        float mx = fmaxf(v0, v1);
        float lse = mx + logf(expf(v0 - mx) + expf(v1 - mx));
        *(float2*)(out + n * OUTC) = make_float2(v0 - lse, v1 - lse);
    }
}

extern "C" void kernel_launch(void* const* d_in, const int* in_sizes, int n_in,
                              void* d_out, int out_size, void* d_ws, size_t ws_size,
                              hipStream_t stream) {
    const float* x  = (const float*)d_in[0];
    const int*   ei = (const int*)d_in[1];
    const float* W1 = (const float*)d_in[2];
    const float* b1 = (const float*)d_in[3];
    const float* W2 = (const float*)d_in[4];
    const float* b2 = (const float*)d_in[5];
    float* out = (float*)d_out;

    const int* src = ei;             // edge_index[0]
    const int* dst = ei + N_EDGES;   // edge_index[1]

    // workspace layout (4B elements)
    int* bc     = (int*)d_ws;                       // NBLK*NB = 102,400
    int* bcount = bc + NBLK * NB;                   // 128
    int* bsum   = bcount + NB;                      // 49
    int* boff   = bsum + SCAN_NB;                   // 49
    int2* bpair = (int2*)(((uintptr_t)(boff + SCAN_NB) + 255) & ~(uintptr_t)255); // 27.1 MB
    int* pcnt   = (int*)(bpair + (size_t)NB * CAP); // S0*NB*SPAN = 1,601,536 (6.4 MB)
    int* cnt    = pcnt + (size_t)S0 * NB * SPAN;    // 100,000
    int* off    = cnt + N_NODES;                    // 100,000
    float* dinv = (float*)(off + N_NODES);          // 100,000
    int* csr    = (int*)(dinv + N_NODES);           // 12.8 MB
    unsigned short* p1b = (unsigned short*)(csr + N_EDGES);   // 3.2 MB
    float* p2b  = (float*)(p1b + (size_t)N_NODES * HID);      // 0.8 MB

    k_count_bb <<<NBLK, 256, 0, stream>>>(dst, bc);
    k_scan_bb  <<<NB, 256, 0, stream>>>(bc, bcount);
    k_fillbkt  <<<NBLK, 256, 0, stream>>>(src, dst, bc, bpair);
    k_cnt_nodes<<<NB * S0, 256, 0, stream>>>(bpair, bcount, pcnt);
    k_cntsum   <<<(N_NODES + 255) / 256, 256, 0, stream>>>(pcnt, cnt, dinv);
    k_blocksum <<<SCAN_NB, 256, 0, stream>>>(cnt, bsum);
    k_scanb    <<<1, 64, 0, stream>>>(bsum, boff);
    k_offsets  <<<SCAN_NB, 256, 0, stream>>>(cnt, boff, off, pcnt);
    k_csrfill  <<<NB * S0, 256, 0, stream>>>(bpair, bcount, pcnt, csr);
    k_gemm1    <<<(N_NODES + 255) / 256, 256, 0, stream>>>(x, W1, dinv, p1b);
    k_gather1  <<<(N_NODES * 16 + 255) / 256, 256, 0, stream>>>(csr, off, cnt, p1b, dinv, b1, W2, p2b);
    k_gather2  <<<(N_NODES * 16 + 255) / 256, 256, 0, stream>>>(csr, off, cnt, p2b, dinv, b2, out);
}

// Round 16
// 143.298 us; speedup vs baseline: 1.1734x; 1.1734x over previous
//
#include <hip/hip_runtime.h>

#define N_NODES 100000
#define N_EDGES 3200000
#define IN_DIM  128
#define HID     16
#define OUTC    2

// bucket geometry: one block can own a whole bucket
#define NB     256                    // dst-range buckets
#define SPAN   391                    // nodes per bucket (256*391 = 100096 >= N)
#define CAP    13250                  // per-bucket capacity (mean 12500, +6σ margin)
#define NBLK   800                    // bucketing blocks
#define BLK_E  (N_EDGES / NBLK)       // 4000

__device__ __forceinline__ unsigned short f2b(float f) {
    unsigned u = __float_as_uint(f);
    unsigned r = u + 0x7FFFu + ((u >> 16) & 1u);   // round-to-nearest-even
    return (unsigned short)(r >> 16);
}
__device__ __forceinline__ float b2f(unsigned short b) {
    return __uint_as_float(((unsigned)b) << 16);
}

// ---------------- K1a: per-(block,bucket) counts ----------------
__global__ __launch_bounds__(256) void k_count_bb(const int* __restrict__ dst,
                                                  int* __restrict__ bc) {
    __shared__ int h[NB];
    h[threadIdx.x] = 0;
    __syncthreads();
    const int4* d4 = (const int4*)(dst + blockIdx.x * BLK_E);
    for (int i = threadIdx.x; i < BLK_E / 4; i += 256) {
        int4 v = d4[i];
        atomicAdd(&h[(unsigned)v.x / SPAN], 1);
        atomicAdd(&h[(unsigned)v.y / SPAN], 1);
        atomicAdd(&h[(unsigned)v.z / SPAN], 1);
        atomicAdd(&h[(unsigned)v.w / SPAN], 1);
    }
    __syncthreads();
    bc[blockIdx.x * NB + threadIdx.x] = h[threadIdx.x];
}

// ---------------- K1b: parallel exclusive scan per bucket over NBLK blocks ----------------
__global__ __launch_bounds__(256) void k_scan_bb(int* __restrict__ bc,
                                                 int* __restrict__ bcount) {
    __shared__ int s[256];
    int b = blockIdx.x;              // bucket
    int base = threadIdx.x * 4;      // 4 block-counts per thread (256*4 >= 800)
    int vals[4];
    int tsum = 0;
#pragma unroll
    for (int i = 0; i < 4; ++i) {
        int t = base + i;
        vals[i] = (t < NBLK) ? bc[t * NB + b] : 0;
        tsum += vals[i];
    }
    s[threadIdx.x] = tsum;
    __syncthreads();
    for (int ofs = 1; ofs < 256; ofs <<= 1) {
        int u = (threadIdx.x >= ofs) ? s[threadIdx.x - ofs] : 0;
        __syncthreads();
        s[threadIdx.x] += u;
        __syncthreads();
    }
    int run = s[threadIdx.x] - tsum;   // exclusive prefix
#pragma unroll
    for (int i = 0; i < 4; ++i) {
        int t = base + i;
        if (t < NBLK) { bc[t * NB + b] = run; run += vals[i]; }
    }
    if (threadIdx.x == 255) bcount[b] = s[255];
}

// ---------------- K1c: fill buckets with (src,dst) int2 pairs ----------------
__global__ __launch_bounds__(256) void k_fillbkt(const int* __restrict__ src,
                                                 const int* __restrict__ dst,
                                                 const int* __restrict__ bc,
                                                 int2* __restrict__ bpair) {
    __shared__ int h[NB];
    __shared__ int gb[NB];
    h[threadIdx.x] = 0;
    gb[threadIdx.x] = threadIdx.x * CAP + bc[blockIdx.x * NB + threadIdx.x];
    __syncthreads();
    const int4* d4 = (const int4*)(dst + blockIdx.x * BLK_E);
    const int4* s4 = (const int4*)(src + blockIdx.x * BLK_E);
    for (int i = threadIdx.x; i < BLK_E / 4; i += 256) {
        int4 dv = d4[i];
        int4 sv = s4[i];
        int b0 = (unsigned)dv.x / SPAN; int p0 = gb[b0] + atomicAdd(&h[b0], 1); bpair[p0] = make_int2(sv.x, dv.x);
        int b1 = (unsigned)dv.y / SPAN; int p1 = gb[b1] + atomicAdd(&h[b1], 1); bpair[p1] = make_int2(sv.y, dv.y);
        int b2 = (unsigned)dv.z / SPAN; int p2 = gb[b2] + atomicAdd(&h[b2], 1); bpair[p2] = make_int2(sv.z, dv.z);
        int b3 = (unsigned)dv.w / SPAN; int p3 = gb[b3] + atomicAdd(&h[b3], 1); bpair[p3] = make_int2(sv.w, dv.w);
    }
}

// ---------------- K2: FUSED per-bucket build: hist -> scan -> cnt/off/dinv -> csr fill ----
// One block owns one whole bucket. Phase 1 streams the bucket's pairs (HBM,
// coalesced) into an LDS degree histogram. The 391-entry exclusive scan plus
// a block-local prefix over bcount[] gives global csr offsets directly.
// Phase 2 re-reads the same pairs (now L2-resident) and places srcs via LDS
// rank cursors. Replaces the 6-kernel CSR-build chain of earlier rounds.
__global__ __launch_bounds__(256) void k_build(const int2* __restrict__ bpair,
                                               const int* __restrict__ bcount,
                                               int* __restrict__ cnt,
                                               int* __restrict__ off,
                                               float* __restrict__ dinv,
                                               int* __restrict__ csr) {
    __shared__ int h[SPAN];
    __shared__ int sc[256];
    __shared__ int csrBase;
    int b = blockIdx.x;
    int t = threadIdx.x;

    // exclusive prefix of bcount -> this bucket's csr base
    int bv = bcount[t];
    sc[t] = bv;
    __syncthreads();
    for (int ofs = 1; ofs < 256; ofs <<= 1) {
        int u = (t >= ofs) ? sc[t - ofs] : 0;
        __syncthreads();
        sc[t] += u;
        __syncthreads();
    }
    if (t == b) csrBase = sc[t] - bv;

    for (int i = t; i < SPAN; i += 256) h[i] = 0;
    __syncthreads();

    int tot = bcount[b];
    int base = b * SPAN;
    const int2* bp = bpair + (size_t)b * CAP;

    // phase 1: degree histogram (coalesced 8B loads, LDS atomics)
    for (int i = t; i < tot; i += 256)
        atomicAdd(&h[bp[i].y - base], 1);
    __syncthreads();

    // exclusive scan of h[0..SPAN), 2 elements per thread
    int i0 = 2 * t, i1 = 2 * t + 1;
    int c0 = (i0 < SPAN) ? h[i0] : 0;
    int c1 = (i1 < SPAN) ? h[i1] : 0;
    int ts = c0 + c1;
    __syncthreads();
    sc[t] = ts;
    __syncthreads();
    for (int ofs = 1; ofs < 256; ofs <<= 1) {
        int u = (t >= ofs) ? sc[t - ofs] : 0;
        __syncthreads();
        sc[t] += u;
        __syncthreads();
    }
    int ex = sc[t] - ts;              // exclusive across thread pairs
    int g0 = csrBase + ex;
    int g1 = g0 + c0;
    __syncthreads();                  // all hist reads done before overwrite
    if (i0 < SPAN) {
        int n = base + i0;
        if (n < N_NODES) { cnt[n] = c0; off[n] = g0; dinv[n] = rsqrtf(1.0f + (float)c0); }
        h[i0] = g0;                   // rank cursor (global csr position)
    }
    if (i1 < SPAN) {
        int n = base + i1;
        if (n < N_NODES) { cnt[n] = c1; off[n] = g1; dinv[n] = rsqrtf(1.0f + (float)c1); }
        h[i1] = g1;
    }
    __syncthreads();

    // phase 2: place (pairs now L2-resident; csr window ~50KB, single-XCD)
    for (int i = t; i < tot; i += 256) {
        int2 e = bp[i];
        int r = atomicAdd(&h[e.y - base], 1);
        csr[r] = e.x;
    }
}

// ---------------- K3: p1b(bf16) = dinv * (x @ W1) — one thread per node ----------------
__global__ __launch_bounds__(256) void k_gemm1(const float* __restrict__ x,
                                               const float* __restrict__ W1,
                                               const float* __restrict__ dinv,
                                               unsigned short* __restrict__ p1b) {
    int n = blockIdx.x * 256 + threadIdx.x;
    if (n >= N_NODES) return;

    float acc[HID];
#pragma unroll
    for (int k = 0; k < HID; ++k) acc[k] = 0.f;

    const float4* xr = (const float4*)(x + (size_t)n * IN_DIM);
#pragma unroll 4
    for (int q = 0; q < IN_DIM / 4; ++q) {
        float4 xv = xr[q];
        const float* wrow = W1 + q * 4 * HID;   // uniform -> scalar loads
#pragma unroll
        for (int k = 0; k < HID; ++k) acc[k] = fmaf(xv.x, wrow[0 * HID + k], acc[k]);
#pragma unroll
        for (int k = 0; k < HID; ++k) acc[k] = fmaf(xv.y, wrow[1 * HID + k], acc[k]);
#pragma unroll
        for (int k = 0; k < HID; ++k) acc[k] = fmaf(xv.z, wrow[2 * HID + k], acc[k]);
#pragma unroll
        for (int k = 0; k < HID; ++k) acc[k] = fmaf(xv.w, wrow[3 * HID + k], acc[k]);
    }

    float di = dinv[n];
    union { unsigned short us[HID]; uint4 v4[2]; } pk;
#pragma unroll
    for (int k = 0; k < HID; ++k) pk.us[k] = f2b(acc[k] * di);
    uint4* op = (uint4*)(p1b + (size_t)n * HID);
    op[0] = pk.v4[0];
    op[1] = pk.v4[1];
}

// ---------------- K4: node-parallel gather 1 (+relu/b1 and W2 fused) ----------------
__global__ __launch_bounds__(256) void k_gather1(const int* __restrict__ csr,
                                                 const int* __restrict__ off,
                                                 const int* __restrict__ cnt,
                                                 const unsigned short* __restrict__ p1b,
                                                 const float* __restrict__ dinv,
                                                 const float* __restrict__ b1,
                                                 const float* __restrict__ W2,
                                                 float* __restrict__ p2b) {
    int gid = blockIdx.x * 256 + threadIdx.x;
    int n = gid >> 4;
    int k = gid & 15;
    if (n >= N_NODES) return;

    int base = off[n];
    int deg = cnt[n];
    float acc = 0.f;
    int j = 0;
    for (; j + 3 < deg; j += 4) {
        int s0 = csr[base + j + 0];
        int s1 = csr[base + j + 1];
        int s2 = csr[base + j + 2];
        int s3 = csr[base + j + 3];
        float v0 = b2f(p1b[s0 * HID + k]);
        float v1 = b2f(p1b[s1 * HID + k]);
        float v2 = b2f(p1b[s2 * HID + k]);
        float v3 = b2f(p1b[s3 * HID + k]);
        acc += (v0 + v1) + (v2 + v3);
    }
    for (; j < deg; ++j) acc += b2f(p1b[csr[base + j] * HID + k]);
    acc += b2f(p1b[n * HID + k]);                // self-loop

    float di = dinv[n];
    float hval = fmaxf(fmaf(di, acc, b1[k]), 0.f);
    float hv = di * hval;
    float t0 = hv * W2[k * OUTC + 0];
    float t1 = hv * W2[k * OUTC + 1];
#pragma unroll
    for (int m = 1; m < HID; m <<= 1) {
        t0 += __shfl_xor(t0, m);
        t1 += __shfl_xor(t1, m);
    }
    if (k == 0) *(float2*)(p2b + n * OUTC) = make_float2(t0, t1);
}

// ---------------- K5: node-parallel gather 2 (+b2/log_softmax fused) ----------------
__global__ __launch_bounds__(256) void k_gather2(const int* __restrict__ csr,
                                                 const int* __restrict__ off,
                                                 const int* __restrict__ cnt,
                                                 const float* __restrict__ p2b,
                                                 const float* __restrict__ dinv,
                                                 const float* __restrict__ b2,
                                                 float* __restrict__ out) {
    int gid = blockIdx.x * 256 + threadIdx.x;
    int n = gid >> 4;
    int k = gid & 15;
    if (n >= N_NODES) return;

    int base = off[n];
    int deg = cnt[n];
    float a0 = 0.f, a1 = 0.f;
    for (int j = k; j < deg; j += 16) {
        int s = csr[base + j];
        float2 v = *(const float2*)(p2b + s * OUTC);
        a0 += v.x;
        a1 += v.y;
    }
    if (k == 0) {                                // self-loop
        float2 v = *(const float2*)(p2b + n * OUTC);
        a0 += v.x;
        a1 += v.y;
    }
#pragma unroll
    for (int m = 1; m < HID; m <<= 1) {
        a0 += __shfl_xor(a0, m);
        a1 += __shfl_xor(a1, m);
    }
    if (k == 0) {
        float di = dinv[n];
        float v0 = fmaf(di, a0, b2[0]);
        float v1 = fmaf(di, a1, b2[1]);
        float mx = fmaxf(v0, v1);
        float lse = mx + logf(expf(v0 - mx) + expf(v1 - mx));
        *(float2*)(out + n * OUTC) = make_float2(v0 - lse, v1 - lse);
    }
}

extern "C" void kernel_launch(void* const* d_in, const int* in_sizes, int n_in,
                              void* d_out, int out_size, void* d_ws, size_t ws_size,
                              hipStream_t stream) {
    const float* x  = (const float*)d_in[0];
    const int*   ei = (const int*)d_in[1];
    const float* W1 = (const float*)d_in[2];
    const float* b1 = (const float*)d_in[3];
    const float* W2 = (const float*)d_in[4];
    const float* b2 = (const float*)d_in[5];
    float* out = (float*)d_out;

    const int* src = ei;             // edge_index[0]
    const int* dst = ei + N_EDGES;   // edge_index[1]

    // workspace layout (4B elements)
    int* bc     = (int*)d_ws;                       // NBLK*NB = 204,800
    int* bcount = bc + NBLK * NB;                   // 256
    int2* bpair = (int2*)(((uintptr_t)(bcount + NB) + 255) & ~(uintptr_t)255); // 27.1 MB
    int* cnt    = (int*)(bpair + (size_t)NB * CAP); // 100,000
    int* off    = cnt + N_NODES;                    // 100,000
    float* dinv = (float*)(off + N_NODES);          // 100,000
    int* csr    = (int*)(dinv + N_NODES);           // 12.8 MB
    unsigned short* p1b = (unsigned short*)(csr + N_EDGES);   // 3.2 MB
    float* p2b  = (float*)(p1b + (size_t)N_NODES * HID);      // 0.8 MB

    k_count_bb <<<NBLK, 256, 0, stream>>>(dst, bc);
    k_scan_bb  <<<NB, 256, 0, stream>>>(bc, bcount);
    k_fillbkt  <<<NBLK, 256, 0, stream>>>(src, dst, bc, bpair);
    k_build    <<<NB, 256, 0, stream>>>(bpair, bcount, cnt, off, dinv, csr);
    k_gemm1    <<<(N_NODES + 255) / 256, 256, 0, stream>>>(x, W1, dinv, p1b);
    k_gather1  <<<(N_NODES * 16 + 255) / 256, 256, 0, stream>>>(csr, off, cnt, p1b, dinv, b1, W2, p2b);
    k_gather2  <<<(N_NODES * 16 + 255) / 256, 256, 0, stream>>>(csr, off, cnt, p2b, dinv, b2, out);
}

// Round 17
// 142.399 us; speedup vs baseline: 1.1808x; 1.0063x over previous
//
#include <hip/hip_runtime.h>

#define N_NODES 100000
#define N_EDGES 3200000
#define IN_DIM  128
#define HID     16
#define OUTC    2

// bucket geometry: one block owns a whole bucket in k_build
#define NB     256                    // dst-range buckets
#define SPAN   391                    // nodes per bucket (256*391 = 100096 >= N)
#define CAP    13250                  // per-bucket capacity (mean 12500, +6.7 sigma)
#define NBLK   1600                   // bucketing blocks
#define BLK_E  (N_EDGES / NBLK)       // 2000
#define VPT    7                      // scan_bb values per thread (256*7 >= 1600)

// packed edge: bits 0..16 = src (100000 < 2^17), bits 17..25 = dst - bucket*SPAN (< 391)
#define PACK(s, ld)  ((unsigned)(s) | ((unsigned)(ld) << 17))
#define P_SRC(p)     ((int)((p) & 0x1FFFFu))
#define P_LDST(p)    ((int)((p) >> 17))

__device__ __forceinline__ unsigned short f2b(float f) {
    unsigned u = __float_as_uint(f);
    unsigned r = u + 0x7FFFu + ((u >> 16) & 1u);   // round-to-nearest-even
    return (unsigned short)(r >> 16);
}
__device__ __forceinline__ float b2f(unsigned short b) {
    return __uint_as_float(((unsigned)b) << 16);
}

// ---------------- K1a: per-(block,bucket) counts ----------------
__global__ __launch_bounds__(256) void k_count_bb(const int* __restrict__ dst,
                                                  int* __restrict__ bc) {
    __shared__ int h[NB];
    h[threadIdx.x] = 0;
    __syncthreads();
    const int4* d4 = (const int4*)(dst + blockIdx.x * BLK_E);
    for (int i = threadIdx.x; i < BLK_E / 4; i += 256) {
        int4 v = d4[i];
        atomicAdd(&h[(unsigned)v.x / SPAN], 1);
        atomicAdd(&h[(unsigned)v.y / SPAN], 1);
        atomicAdd(&h[(unsigned)v.z / SPAN], 1);
        atomicAdd(&h[(unsigned)v.w / SPAN], 1);
    }
    __syncthreads();
    bc[blockIdx.x * NB + threadIdx.x] = h[threadIdx.x];
}

// ---------------- K1b: parallel exclusive scan per bucket over NBLK blocks ----------------
__global__ __launch_bounds__(256) void k_scan_bb(int* __restrict__ bc,
                                                 int* __restrict__ bcount) {
    __shared__ int s[256];
    int b = blockIdx.x;              // bucket
    int base = threadIdx.x * VPT;
    int vals[VPT];
    int tsum = 0;
#pragma unroll
    for (int i = 0; i < VPT; ++i) {
        int t = base + i;
        vals[i] = (t < NBLK) ? bc[t * NB + b] : 0;
        tsum += vals[i];
    }
    s[threadIdx.x] = tsum;
    __syncthreads();
    for (int ofs = 1; ofs < 256; ofs <<= 1) {
        int u = (threadIdx.x >= ofs) ? s[threadIdx.x - ofs] : 0;
        __syncthreads();
        s[threadIdx.x] += u;
        __syncthreads();
    }
    int run = s[threadIdx.x] - tsum;   // exclusive prefix
#pragma unroll
    for (int i = 0; i < VPT; ++i) {
        int t = base + i;
        if (t < NBLK) { bc[t * NB + b] = run; run += vals[i]; }
    }
    if (threadIdx.x == 255) bcount[b] = s[255];
}

// ---------------- K1c: fill buckets with packed 4B edges ----------------
__global__ __launch_bounds__(256) void k_fillbkt(const int* __restrict__ src,
                                                 const int* __restrict__ dst,
                                                 const int* __restrict__ bc,
                                                 unsigned* __restrict__ bpack) {
    __shared__ int h[NB];
    __shared__ int gb[NB];
    h[threadIdx.x] = 0;
    gb[threadIdx.x] = threadIdx.x * CAP + bc[blockIdx.x * NB + threadIdx.x];
    __syncthreads();
    const int4* d4 = (const int4*)(dst + blockIdx.x * BLK_E);
    const int4* s4 = (const int4*)(src + blockIdx.x * BLK_E);
    for (int i = threadIdx.x; i < BLK_E / 4; i += 256) {
        int4 dv = d4[i];
        int4 sv = s4[i];
        int b0 = (unsigned)dv.x / SPAN; int p0 = gb[b0] + atomicAdd(&h[b0], 1); bpack[p0] = PACK(sv.x, dv.x - b0 * SPAN);
        int b1 = (unsigned)dv.y / SPAN; int p1 = gb[b1] + atomicAdd(&h[b1], 1); bpack[p1] = PACK(sv.y, dv.y - b1 * SPAN);
        int b2 = (unsigned)dv.z / SPAN; int p2 = gb[b2] + atomicAdd(&h[b2], 1); bpack[p2] = PACK(sv.z, dv.z - b2 * SPAN);
        int b3 = (unsigned)dv.w / SPAN; int p3 = gb[b3] + atomicAdd(&h[b3], 1); bpack[p3] = PACK(sv.w, dv.w - b3 * SPAN);
    }
}

// ---------------- K2: FUSED per-bucket build: hist -> scan -> cnt/off/dinv -> csr fill ----
__global__ __launch_bounds__(256) void k_build(const unsigned* __restrict__ bpack,
                                               const int* __restrict__ bcount,
                                               int* __restrict__ cnt,
                                               int* __restrict__ off,
                                               float* __restrict__ dinv,
                                               int* __restrict__ csr) {
    __shared__ int h[SPAN];
    __shared__ int sc[256];
    __shared__ int csrBase;
    int b = blockIdx.x;
    int t = threadIdx.x;

    // exclusive prefix of bcount -> this bucket's csr base
    int bv = bcount[t];
    sc[t] = bv;
    __syncthreads();
    for (int ofs = 1; ofs < 256; ofs <<= 1) {
        int u = (t >= ofs) ? sc[t - ofs] : 0;
        __syncthreads();
        sc[t] += u;
        __syncthreads();
    }
    if (t == b) csrBase = sc[t] - bv;

    for (int i = t; i < SPAN; i += 256) h[i] = 0;
    __syncthreads();

    int tot = bcount[b];
    const unsigned* bp = bpack + (size_t)b * CAP;

    // phase 1: degree histogram (coalesced 4B loads, LDS atomics)
    for (int i = t; i < tot; i += 256)
        atomicAdd(&h[P_LDST(bp[i])], 1);
    __syncthreads();

    // exclusive scan of h[0..SPAN), 2 elements per thread
    int base = b * SPAN;
    int i0 = 2 * t, i1 = 2 * t + 1;
    int c0 = (i0 < SPAN) ? h[i0] : 0;
    int c1 = (i1 < SPAN) ? h[i1] : 0;
    int ts = c0 + c1;
    __syncthreads();
    sc[t] = ts;
    __syncthreads();
    for (int ofs = 1; ofs < 256; ofs <<= 1) {
        int u = (t >= ofs) ? sc[t - ofs] : 0;
        __syncthreads();
        sc[t] += u;
        __syncthreads();
    }
    int ex = sc[t] - ts;
    int g0 = csrBase + ex;
    int g1 = g0 + c0;
    __syncthreads();                  // all hist reads done before overwrite
    if (i0 < SPAN) {
        int n = base + i0;
        if (n < N_NODES) { cnt[n] = c0; off[n] = g0; dinv[n] = rsqrtf(1.0f + (float)c0); }
        h[i0] = g0;                   // rank cursor (global csr position)
    }
    if (i1 < SPAN) {
        int n = base + i1;
        if (n < N_NODES) { cnt[n] = c1; off[n] = g1; dinv[n] = rsqrtf(1.0f + (float)c1); }
        h[i1] = g1;
    }
    __syncthreads();

    // phase 2: place (pairs now L2-resident; csr window ~50KB, single-XCD)
    for (int i = t; i < tot; i += 256) {
        unsigned e = bp[i];
        int r = atomicAdd(&h[P_LDST(e)], 1);
        csr[r] = P_SRC(e);
    }
}

// ---------------- K3: p1b(bf16) = dinv * (x @ W1) — one thread per node ----------------
__global__ __launch_bounds__(256) void k_gemm1(const float* __restrict__ x,
                                               const float* __restrict__ W1,
                                               const float* __restrict__ dinv,
                                               unsigned short* __restrict__ p1b) {
    int n = blockIdx.x * 256 + threadIdx.x;
    if (n >= N_NODES) return;

    float acc[HID];
#pragma unroll
    for (int k = 0; k < HID; ++k) acc[k] = 0.f;

    const float4* xr = (const float4*)(x + (size_t)n * IN_DIM);
#pragma unroll 4
    for (int q = 0; q < IN_DIM / 4; ++q) {
        float4 xv = xr[q];
        const float* wrow = W1 + q * 4 * HID;   // uniform -> scalar loads
#pragma unroll
        for (int k = 0; k < HID; ++k) acc[k] = fmaf(xv.x, wrow[0 * HID + k], acc[k]);
#pragma unroll
        for (int k = 0; k < HID; ++k) acc[k] = fmaf(xv.y, wrow[1 * HID + k], acc[k]);
#pragma unroll
        for (int k = 0; k < HID; ++k) acc[k] = fmaf(xv.z, wrow[2 * HID + k], acc[k]);
#pragma unroll
        for (int k = 0; k < HID; ++k) acc[k] = fmaf(xv.w, wrow[3 * HID + k], acc[k]);
    }

    float di = dinv[n];
    union { unsigned short us[HID]; uint4 v4[2]; } pk;
#pragma unroll
    for (int k = 0; k < HID; ++k) pk.us[k] = f2b(acc[k] * di);
    uint4* op = (uint4*)(p1b + (size_t)n * HID);
    op[0] = pk.v4[0];
    op[1] = pk.v4[1];
}

// ---------------- K4: node-parallel gather 1 (+relu/b1 and W2 fused) ----------------
__global__ __launch_bounds__(256) void k_gather1(const int* __restrict__ csr,
                                                 const int* __restrict__ off,
                                                 const int* __restrict__ cnt,
                                                 const unsigned short* __restrict__ p1b,
                                                 const float* __restrict__ dinv,
                                                 const float* __restrict__ b1,
                                                 const float* __restrict__ W2,
                                                 float* __restrict__ p2b) {
    int gid = blockIdx.x * 256 + threadIdx.x;
    int n = gid >> 4;
    int k = gid & 15;
    if (n >= N_NODES) return;

    int base = off[n];
    int deg = cnt[n];
    float acc = 0.f;
    int j = 0;
    for (; j + 3 < deg; j += 4) {
        int s0 = csr[base + j + 0];
        int s1 = csr[base + j + 1];
        int s2 = csr[base + j + 2];
        int s3 = csr[base + j + 3];
        float v0 = b2f(p1b[s0 * HID + k]);
        float v1 = b2f(p1b[s1 * HID + k]);
        float v2 = b2f(p1b[s2 * HID + k]);
        float v3 = b2f(p1b[s3 * HID + k]);
        acc += (v0 + v1) + (v2 + v3);
    }
    for (; j < deg; ++j) acc += b2f(p1b[csr[base + j] * HID + k]);
    acc += b2f(p1b[n * HID + k]);                // self-loop

    float di = dinv[n];
    float hval = fmaxf(fmaf(di, acc, b1[k]), 0.f);
    float hv = di * hval;
    float t0 = hv * W2[k * OUTC + 0];
    float t1 = hv * W2[k * OUTC + 1];
#pragma unroll
    for (int m = 1; m < HID; m <<= 1) {
        t0 += __shfl_xor(t0, m);
        t1 += __shfl_xor(t1, m);
    }
    if (k == 0) *(float2*)(p2b + n * OUTC) = make_float2(t0, t1);
}

// ---------------- K5: node-parallel gather 2 (+b2/log_softmax fused) ----------------
__global__ __launch_bounds__(256) void k_gather2(const int* __restrict__ csr,
                                                 const int* __restrict__ off,
                                                 const int* __restrict__ cnt,
                                                 const float* __restrict__ p2b,
                                                 const float* __restrict__ dinv,
                                                 const float* __restrict__ b2,
                                                 float* __restrict__ out) {
    int gid = blockIdx.x * 256 + threadIdx.x;
    int n = gid >> 4;
    int k = gid & 15;
    if (n >= N_NODES) return;

    int base = off[n];
    int deg = cnt[n];
    float a0 = 0.f, a1 = 0.f;
    for (int j = k; j < deg; j += 16) {
        int s = csr[base + j];
        float2 v = *(const float2*)(p2b + s * OUTC);
        a0 += v.x;
        a1 += v.y;
    }
    if (k == 0) {                                // self-loop
        float2 v = *(const float2*)(p2b + n * OUTC);
        a0 += v.x;
        a1 += v.y;
    }
#pragma unroll
    for (int m = 1; m < HID; m <<= 1) {
        a0 += __shfl_xor(a0, m);
        a1 += __shfl_xor(a1, m);
    }
    if (k == 0) {
        float di = dinv[n];
        float v0 = fmaf(di, a0, b2[0]);
        float v1 = fmaf(di, a1, b2[1]);
        float mx = fmaxf(v0, v1);
        float lse = mx + logf(expf(v0 - mx) + expf(v1 - mx));
        *(float2*)(out + n * OUTC) = make_float2(v0 - lse, v1 - lse);
    }
}

extern "C" void kernel_launch(void* const* d_in, const int* in_sizes, int n_in,
                              void* d_out, int out_size, void* d_ws, size_t ws_size,
                              hipStream_t stream) {
    const float* x  = (const float*)d_in[0];
    const int*   ei = (const int*)d_in[1];
    const float* W1 = (const float*)d_in[2];
    const float* b1 = (const float*)d_in[3];
    const float* W2 = (const float*)d_in[4];
    const float* b2 = (const float*)d_in[5];
    float* out = (float*)d_out;

    const int* src = ei;             // edge_index[0]
    const int* dst = ei + N_EDGES;   // edge_index[1]

    // workspace layout (4B elements)
    int* bc     = (int*)d_ws;                       // NBLK*NB = 409,600 (1.6 MB)
    int* bcount = bc + NBLK * NB;                   // 256
    unsigned* bpack = (unsigned*)(((uintptr_t)(bcount + NB) + 255) & ~(uintptr_t)255); // 13.6 MB
    int* cnt    = (int*)(bpack + (size_t)NB * CAP); // 100,000
    int* off    = cnt + N_NODES;                    // 100,000
    float* dinv = (float*)(off + N_NODES);          // 100,000
    int* csr    = (int*)(dinv + N_NODES);           // 12.8 MB
    unsigned short* p1b = (unsigned short*)(csr + N_EDGES);   // 3.2 MB
    float* p2b  = (float*)(p1b + (size_t)N_NODES * HID);      // 0.8 MB

    k_count_bb <<<NBLK, 256, 0, stream>>>(dst, bc);
    k_scan_bb  <<<NB, 256, 0, stream>>>(bc, bcount);
    k_fillbkt  <<<NBLK, 256, 0, stream>>>(src, dst, bc, bpack);
    k_build    <<<NB, 256, 0, stream>>>(bpack, bcount, cnt, off, dinv, csr);
    k_gemm1    <<<(N_NODES + 255) / 256, 256, 0, stream>>>(x, W1, dinv, p1b);
    k_gather1  <<<(N_NODES * 16 + 255) / 256, 256, 0, stream>>>(csr, off, cnt, p1b, dinv, b1, W2, p2b);
    k_gather2  <<<(N_NODES * 16 + 255) / 256, 256, 0, stream>>>(csr, off, cnt, p2b, dinv, b2, out);
}